// Round 2
// baseline (1354.185 us; speedup 1.0000x reference)
//
#include <hip/hip_runtime.h>

#define NB 32
#define NGT 100
#define NL 8400
#define NC 80
#define KTOP 13
#define TL 64

__device__ __forceinline__ float clamp0(float x) { return fmaxf(x, 0.f); }

// ---------------- Transpose: ps [b, l, c] -> pst [b, c, l] ----------------
__global__ __launch_bounds__(256) void transpose_kernel(
    const float* __restrict__ ps, float* __restrict__ pst)
{
  __shared__ float tile[TL][NC + 1];
  const int b = blockIdx.y;
  const int l0 = blockIdx.x * TL;
  const int nl = min(TL, NL - l0);
  for (int i = threadIdx.x; i < nl * 20; i += 256) {
    int r = i / 20, cv = i % 20;
    float4 v = ((const float4*)(ps + ((size_t)b * NL + l0 + r) * NC))[cv];
    tile[r][cv * 4 + 0] = v.x; tile[r][cv * 4 + 1] = v.y;
    tile[r][cv * 4 + 2] = v.z; tile[r][cv * 4 + 3] = v.w;
  }
  __syncthreads();
  for (int i = threadIdx.x; i < NC * TL; i += 256) {
    int c = i >> 6, r = i & 63;
    if (r < nl)
      pst[((size_t)b * NC + c) * NL + l0 + r] = tile[r][c];
  }
}

// ---------------- Kernel A: per-(b,n) metric + stable top-13 ----------------
__global__ __launch_bounds__(256) void topk_kernel(
    const float* __restrict__ ps, const float* __restrict__ pst,
    const float* __restrict__ pb, const float* __restrict__ ap,
    const int* __restrict__ gl, const float* __restrict__ gtb,
    int* __restrict__ topk_out)
{
  __shared__ float met[NL];
  __shared__ unsigned long long red[256];
  const int bn = blockIdx.x;
  const int b = bn / NGT;
  const float gx1 = gtb[bn * 4 + 0], gy1 = gtb[bn * 4 + 1];
  const float gx2 = gtb[bn * 4 + 2], gy2 = gtb[bn * 4 + 3];
  const int cls = gl[bn];
  const float ga = clamp0(gx2 - gx1) * clamp0(gy2 - gy1);
  const float4* pbb = (const float4*)pb + (size_t)b * NL;
  const float* psb = ps + (size_t)b * NL * NC;
  const float* scp = pst ? pst + ((size_t)b * NC + cls) * NL : nullptr;
  const float2* apb = (const float2*)ap;

  for (int l = threadIdx.x; l < NL; l += 256) {
    float4 p = pbb[l];
    float ox = fminf(p.z, gx2) - fmaxf(p.x, gx1);
    float oy = fminf(p.w, gy2) - fmaxf(p.y, gy1);
    float ov = clamp0(ox) * clamp0(oy);
    float pa = clamp0(p.z - p.x) * clamp0(p.w - p.y);
    float iou = ov / (ga + pa - ov + 1e-9f);
    float2 a = apb[l];
    float ins = (fminf(fminf(a.x - gx1, a.y - gy1),
                       fminf(gx2 - a.x, gy2 - a.y)) > 1e-9f) ? 1.f : 0.f;
    float sc = scp ? scp[l] : psb[(size_t)l * NC + cls];
    float i2 = iou * iou;
    met[l] = sc * i2 * i2 * i2 * ins;
  }
  __syncthreads();

  // 13 rounds of argmax (value desc, index asc) == jax.lax.top_k tie semantics
  for (int k = 0; k < KTOP; ++k) {
    unsigned long long best = 0ull;
    for (int l = threadIdx.x; l < NL; l += 256) {
      float v = met[l];
      if (v >= 0.f) {  // marked entries are -1.f
        unsigned long long key =
            ((unsigned long long)__float_as_uint(v) << 32) |
            (unsigned long long)(0xFFFFFFFFu - (unsigned)l);
        if (key > best) best = key;
      }
    }
    red[threadIdx.x] = best;
    __syncthreads();
    for (int s = 128; s > 0; s >>= 1) {
      if (threadIdx.x < s) {
        unsigned long long o = red[threadIdx.x + s];
        if (o > red[threadIdx.x]) red[threadIdx.x] = o;
      }
      __syncthreads();
    }
    int idx = (int)(0xFFFFFFFFu - (unsigned)(red[0] & 0xFFFFFFFFull));
    if (threadIdx.x == 0) {
      topk_out[bn * KTOP + k] = idx;
      met[idx] = -1.f;
    }
    __syncthreads();
  }
}

// ------------- Kernel B: per-(b,l) assignment (n*, align*, iou*) -------------
__global__ __launch_bounds__(256) void assign_kernel(
    const float* __restrict__ ps, const float* __restrict__ pb,
    const float* __restrict__ ap, const int* __restrict__ gl,
    const float* __restrict__ gtb, const float* __restrict__ pad,
    const int* __restrict__ topk, int* __restrict__ nstar,
    float* __restrict__ astar, unsigned* __restrict__ maxm,
    unsigned* __restrict__ maxi)
{
  __shared__ float4 sgt[NGT];
  __shared__ int sgl[NGT];
  __shared__ float spad[NGT];
  __shared__ int stopk[NGT * KTOP];
  const int b = blockIdx.y;
  for (int i = threadIdx.x; i < NGT; i += 256) {
    sgt[i] = ((const float4*)gtb)[b * NGT + i];
    sgl[i] = gl[b * NGT + i];
    spad[i] = pad[b * NGT + i];
  }
  for (int i = threadIdx.x; i < NGT * KTOP; i += 256)
    stopk[i] = topk[b * NGT * KTOP + i];
  __syncthreads();

  const int l = blockIdx.x * 256 + threadIdx.x;
  if (l >= NL) return;

  float4 p = ((const float4*)pb)[(size_t)b * NL + l];
  float2 a = ((const float2*)ap)[l];
  float pa = clamp0(p.z - p.x) * clamp0(p.w - p.y);

  int mps = 0, n_single = -1, max_n = 0;
  float iou_single = 0.f, max_iou = -1.f;
  for (int n = 0; n < NGT; ++n) {
    float4 g = sgt[n];
    float ox = fminf(p.z, g.z) - fmaxf(p.x, g.x);
    float oy = fminf(p.w, g.w) - fmaxf(p.y, g.y);
    float ov = clamp0(ox) * clamp0(oy);
    float ga = clamp0(g.z - g.x) * clamp0(g.w - g.y);
    float iou = ov / (ga + pa - ov + 1e-9f);
    if (iou > max_iou) { max_iou = iou; max_n = n; }  // argmax over ALL n (incl. pad)
    bool ins = fminf(fminf(a.x - g.x, a.y - g.y),
                     fminf(g.z - a.x, g.w - a.y)) > 1e-9f;
    if (ins && spad[n] != 0.f) {
      bool hit = false;
#pragma unroll
      for (int k = 0; k < KTOP; ++k) hit |= (stopk[n * KTOP + k] == l);
      if (hit) { mps++; n_single = n; iou_single = iou; }
    }
  }

  int ns; float iou_s;
  if (mps == 0)      { ns = -1;       iou_s = 0.f; }
  else if (mps == 1) { ns = n_single; iou_s = iou_single; }
  else               { ns = max_n;    iou_s = max_iou; }  // is_max_iou replacement

  float al_s = 0.f;
  if (ns >= 0) {
    float sc = ps[((size_t)b * NL + l) * NC + sgl[ns]];
    float i2 = iou_s * iou_s;
    al_s = sc * i2 * i2 * i2;
    atomicMax(&maxm[b * NGT + ns], __float_as_uint(al_s));
    atomicMax(&maxi[b * NGT + ns], __float_as_uint(iou_s));
  }
  nstar[b * NL + l] = ns;
  astar[b * NL + l] = al_s;
}

// ------- Kernel C1: per-(b,l) scale/class + GIoU term + scale sums ---------
__global__ __launch_bounds__(256) void scale_kernel(
    const float* __restrict__ pb, const float* __restrict__ gtb,
    const int* __restrict__ gl, const int* __restrict__ nstar,
    const float* __restrict__ astar, const unsigned* __restrict__ maxm,
    const unsigned* __restrict__ maxi, float* __restrict__ scale_arr,
    int* __restrict__ jcls, double* __restrict__ acc)
{
  const int b = blockIdx.y;
  const int l = blockIdx.x * 256 + threadIdx.x;
  double isum = 0.0, as = 0.0;
  if (l < NL) {
    int ns = nstar[b * NL + l];
    float scale = 0.f;
    int j = NC;
    if (ns >= 0) {
      float mm = __uint_as_float(maxm[b * NGT + ns]);
      float mi = __uint_as_float(maxi[b * NGT + ns]);
      scale = astar[b * NL + l] / (mm + 1e-9f) * mi;
      j = gl[b * NGT + ns];
      as = (double)scale;
      float4 p = ((const float4*)pb)[(size_t)b * NL + l];
      float4 g = ((const float4*)gtb)[b * NGT + ns];
      float x1 = fmaxf(p.x, g.x), y1 = fmaxf(p.y, g.y);
      float x2 = fminf(p.z, g.z), y2 = fminf(p.w, g.w);
      float ov = clamp0(x2 - x1) * clamp0(y2 - y1);
      float pa = clamp0(p.z - p.x) * clamp0(p.w - p.y);
      float ga = clamp0(g.z - g.x) * clamp0(g.w - g.y);
      float un = pa + ga - ov + 1e-10f;
      float iou = ov / un;
      float cx1 = fminf(p.x, g.x), cy1 = fminf(p.y, g.y);
      float cx2 = fmaxf(p.z, g.z), cy2 = fmaxf(p.w, g.w);
      float cc = clamp0(cx2 - cx1) * clamp0(cy2 - cy1) + 1e-10f;
      float gi = 1.f - (iou - (cc - un) / cc);
      isum = (double)(gi * scale);
    }
    scale_arr[b * NL + l] = scale;
    jcls[b * NL + l] = j;
  }
  for (int off = 32; off > 0; off >>= 1) {
    isum += __shfl_down(isum, off);
    as += __shfl_down(as, off);
  }
  if ((threadIdx.x & 63) == 0) {
    atomicAdd(&acc[1], isum);
    atomicAdd(&acc[2], as);
  }
}

// ---------- Kernel C2: coalesced VFL-BCE, one float4 of ps per thread -------
__global__ __launch_bounds__(256) void vfl_kernel(
    const float* __restrict__ ps, const float* __restrict__ scale_arr,
    const int* __restrict__ jcls, double* __restrict__ acc)
{
  const size_t gid = (size_t)blockIdx.x * 256 + threadIdx.x;  // float4 index
  double cs = 0.0;
  {
    const size_t row = gid / 20;
    const int c0 = (int)(gid % 20) * 4;
    float4 s4 = ((const float4*)ps)[gid];
    float scale = scale_arr[row];
    int j = jcls[row];
    float sv[4] = {s4.x, s4.y, s4.z, s4.w};
    float csum = 0.f;
#pragma unroll
    for (int u = 0; u < 4; ++u) {
      float s = sv[u];
      float pcl = fminf(fmaxf(s, 1e-9f), 1.f - 1e-9f);
      float lp1 = log1pf(-pcl);
      if (c0 + u == j)
        csum += -(scale * logf(pcl) + (1.f - scale) * lp1) * scale;
      else
        csum += -lp1 * 0.75f * s * s;
    }
    cs = (double)csum;
  }
  for (int off = 32; off > 0; off >>= 1) cs += __shfl_down(cs, off);
  if ((threadIdx.x & 63) == 0) atomicAdd(&acc[0], cs);
}

__global__ void fin_kernel(const double* __restrict__ acc, float* __restrict__ out) {
  double s = acc[2] > 1.0 ? acc[2] : 1.0;
  out[0] = (float)((acc[0] + 2.5 * acc[1]) / s);
}

// ---------------------------------------------------------------------------
extern "C" void kernel_launch(void* const* d_in, const int* in_sizes, int n_in,
                              void* d_out, int out_size, void* d_ws, size_t ws_size,
                              hipStream_t stream) {
  const float* ps  = (const float*)d_in[0];   // [32,8400,80]
  const float* pbx = (const float*)d_in[1];   // [32,8400,4]
  const float* ap  = (const float*)d_in[2];   // [8400,2]
  const int*   gl  = (const int*)d_in[3];     // [32,100,1]
  const float* gtb = (const float*)d_in[4];   // [32,100,4]
  const float* pad = (const float*)d_in[5];   // [32,100,1]

  char* ws = (char*)d_ws;
  const size_t OFF_ACC   = 0;                                // 3 doubles
  const size_t OFF_MAXM  = 32;                               // 3200 u32
  const size_t OFF_MAXI  = OFF_MAXM + 4ul * NB * NGT;        // 3200 u32
  const size_t OFF_TOPK  = OFF_MAXI + 4ul * NB * NGT;        // 41600 i32
  const size_t OFF_NSTAR = OFF_TOPK + 4ul * NB * NGT * KTOP; // 268800 i32
  const size_t OFF_ASTAR = OFF_NSTAR + 4ul * NB * NL;        // 268800 f32
  const size_t OFF_SCALE = OFF_ASTAR + 4ul * NB * NL;        // 268800 f32
  const size_t OFF_JCLS  = OFF_SCALE + 4ul * NB * NL;        // 268800 i32
  const size_t OFF_PST   = OFF_JCLS + 4ul * NB * NL;         // 21.5M f32 (86 MB)
  const size_t PST_BYTES = 4ul * NB * NC * NL;

  double*   acc   = (double*)(ws + OFF_ACC);
  unsigned* maxm  = (unsigned*)(ws + OFF_MAXM);
  unsigned* maxi  = (unsigned*)(ws + OFF_MAXI);
  int*      topk  = (int*)(ws + OFF_TOPK);
  int*      nstar = (int*)(ws + OFF_NSTAR);
  float*    astar = (float*)(ws + OFF_ASTAR);
  float*    scale_arr = (float*)(ws + OFF_SCALE);
  int*      jcls  = (int*)(ws + OFF_JCLS);
  float*    pst   = (ws_size >= OFF_PST + PST_BYTES) ? (float*)(ws + OFF_PST) : nullptr;

  hipMemsetAsync(ws, 0, OFF_TOPK, stream);  // zero acc + maxm + maxi

  if (pst)
    hipLaunchKernelGGL(transpose_kernel, dim3((NL + TL - 1) / TL, NB), dim3(256),
                       0, stream, ps, pst);
  hipLaunchKernelGGL(topk_kernel, dim3(NB * NGT), dim3(256), 0, stream,
                     ps, pst, pbx, ap, gl, gtb, topk);
  hipLaunchKernelGGL(assign_kernel, dim3((NL + 255) / 256, NB), dim3(256), 0, stream,
                     ps, pbx, ap, gl, gtb, pad, topk, nstar, astar, maxm, maxi);
  hipLaunchKernelGGL(scale_kernel, dim3((NL + 255) / 256, NB), dim3(256), 0, stream,
                     pbx, gtb, gl, nstar, astar, maxm, maxi, scale_arr, jcls, acc);
  hipLaunchKernelGGL(vfl_kernel, dim3((NB * (size_t)NL * 20) / 256), dim3(256),
                     0, stream, ps, scale_arr, jcls, acc);
  hipLaunchKernelGGL(fin_kernel, dim3(1), dim3(1), 0, stream, acc, (float*)d_out);
}

// Round 3
// 281.389 us; speedup vs baseline: 4.8125x; 4.8125x over previous
//
#include <hip/hip_runtime.h>

#define NB 32
#define NGT 100
#define NL 8400
#define NC 80
#define KTOP 13
#define TL 64
#define VFL_BLOCKS 2048
#define SC_BLOCKS_X 33   // ceil(8400/256)
#define SC_BLOCKS (SC_BLOCKS_X * NB)

__device__ __forceinline__ float clamp0(float x) { return fmaxf(x, 0.f); }

// Block-reduce a double (256 threads); result valid on thread 0.
__device__ __forceinline__ double block_red(double v, double* sred) {
  for (int off = 32; off > 0; off >>= 1) v += __shfl_down(v, off);
  int wid = threadIdx.x >> 6;
  if ((threadIdx.x & 63) == 0) sred[wid] = v;
  __syncthreads();
  double r = 0.0;
  if (threadIdx.x == 0) r = sred[0] + sred[1] + sred[2] + sred[3];
  __syncthreads();
  return r;
}

// ---------------- Transpose: ps [b, l, c] -> pst [b, c, l] ----------------
__global__ __launch_bounds__(256) void transpose_kernel(
    const float* __restrict__ ps, float* __restrict__ pst)
{
  __shared__ float tile[TL][NC + 1];
  const int b = blockIdx.y;
  const int l0 = blockIdx.x * TL;
  const int nl = min(TL, NL - l0);
  for (int i = threadIdx.x; i < nl * 20; i += 256) {
    int r = i / 20, cv = i % 20;
    float4 v = ((const float4*)(ps + ((size_t)b * NL + l0 + r) * NC))[cv];
    tile[r][cv * 4 + 0] = v.x; tile[r][cv * 4 + 1] = v.y;
    tile[r][cv * 4 + 2] = v.z; tile[r][cv * 4 + 3] = v.w;
  }
  __syncthreads();
  for (int i = threadIdx.x; i < NC * TL; i += 256) {
    int c = i >> 6, r = i & 63;
    if (r < nl)
      pst[((size_t)b * NC + c) * NL + l0 + r] = tile[r][c];
  }
}

// ---------------- Kernel A: per-(b,n) metric + stable top-13 ----------------
__global__ __launch_bounds__(256) void topk_kernel(
    const float* __restrict__ ps, const float* __restrict__ pst,
    const float* __restrict__ pb, const float* __restrict__ ap,
    const int* __restrict__ gl, const float* __restrict__ gtb,
    int* __restrict__ topk_out)
{
  __shared__ float met[NL];
  __shared__ unsigned long long red[256];
  const int bn = blockIdx.x;
  const int b = bn / NGT;
  const float gx1 = gtb[bn * 4 + 0], gy1 = gtb[bn * 4 + 1];
  const float gx2 = gtb[bn * 4 + 2], gy2 = gtb[bn * 4 + 3];
  const int cls = gl[bn];
  const float ga = clamp0(gx2 - gx1) * clamp0(gy2 - gy1);
  const float4* pbb = (const float4*)pb + (size_t)b * NL;
  const float* psb = ps + (size_t)b * NL * NC;
  const float* scp = pst ? pst + ((size_t)b * NC + cls) * NL : nullptr;
  const float2* apb = (const float2*)ap;

  for (int l = threadIdx.x; l < NL; l += 256) {
    float4 p = pbb[l];
    float ox = fminf(p.z, gx2) - fmaxf(p.x, gx1);
    float oy = fminf(p.w, gy2) - fmaxf(p.y, gy1);
    float ov = clamp0(ox) * clamp0(oy);
    float pa = clamp0(p.z - p.x) * clamp0(p.w - p.y);
    float iou = ov / (ga + pa - ov + 1e-9f);
    float2 a = apb[l];
    float ins = (fminf(fminf(a.x - gx1, a.y - gy1),
                       fminf(gx2 - a.x, gy2 - a.y)) > 1e-9f) ? 1.f : 0.f;
    float sc = scp ? scp[l] : psb[(size_t)l * NC + cls];
    float i2 = iou * iou;
    met[l] = sc * i2 * i2 * i2 * ins;
  }
  __syncthreads();

  // 13 rounds of argmax (value desc, index asc) == jax.lax.top_k tie semantics
  for (int k = 0; k < KTOP; ++k) {
    unsigned long long best = 0ull;
    for (int l = threadIdx.x; l < NL; l += 256) {
      float v = met[l];
      if (v >= 0.f) {  // marked entries are -1.f
        unsigned long long key =
            ((unsigned long long)__float_as_uint(v) << 32) |
            (unsigned long long)(0xFFFFFFFFu - (unsigned)l);
        if (key > best) best = key;
      }
    }
    red[threadIdx.x] = best;
    __syncthreads();
    for (int s = 128; s > 0; s >>= 1) {
      if (threadIdx.x < s) {
        unsigned long long o = red[threadIdx.x + s];
        if (o > red[threadIdx.x]) red[threadIdx.x] = o;
      }
      __syncthreads();
    }
    int idx = (int)(0xFFFFFFFFu - (unsigned)(red[0] & 0xFFFFFFFFull));
    if (threadIdx.x == 0) {
      topk_out[bn * KTOP + k] = idx;
      met[idx] = -1.f;
    }
    __syncthreads();
  }
}

// ------------- Kernel B: per-(b,l) assignment (n*, align*, iou*) -------------
__global__ __launch_bounds__(256) void assign_kernel(
    const float* __restrict__ ps, const float* __restrict__ pb,
    const float* __restrict__ ap, const int* __restrict__ gl,
    const float* __restrict__ gtb, const float* __restrict__ pad,
    const int* __restrict__ topk, int* __restrict__ nstar,
    float* __restrict__ astar, unsigned* __restrict__ maxm,
    unsigned* __restrict__ maxi)
{
  __shared__ float4 sgt[NGT];
  __shared__ int sgl[NGT];
  __shared__ float spad[NGT];
  __shared__ int stopk[NGT * KTOP];
  const int b = blockIdx.y;
  for (int i = threadIdx.x; i < NGT; i += 256) {
    sgt[i] = ((const float4*)gtb)[b * NGT + i];
    sgl[i] = gl[b * NGT + i];
    spad[i] = pad[b * NGT + i];
  }
  for (int i = threadIdx.x; i < NGT * KTOP; i += 256)
    stopk[i] = topk[b * NGT * KTOP + i];
  __syncthreads();

  const int l = blockIdx.x * 256 + threadIdx.x;
  if (l >= NL) return;

  float4 p = ((const float4*)pb)[(size_t)b * NL + l];
  float2 a = ((const float2*)ap)[l];
  float pa = clamp0(p.z - p.x) * clamp0(p.w - p.y);

  int mps = 0, n_single = -1, max_n = 0;
  float iou_single = 0.f, max_iou = -1.f;
  for (int n = 0; n < NGT; ++n) {
    float4 g = sgt[n];
    float ox = fminf(p.z, g.z) - fmaxf(p.x, g.x);
    float oy = fminf(p.w, g.w) - fmaxf(p.y, g.y);
    float ov = clamp0(ox) * clamp0(oy);
    float ga = clamp0(g.z - g.x) * clamp0(g.w - g.y);
    float iou = ov / (ga + pa - ov + 1e-9f);
    if (iou > max_iou) { max_iou = iou; max_n = n; }  // argmax over ALL n (incl. pad)
    bool ins = fminf(fminf(a.x - g.x, a.y - g.y),
                     fminf(g.z - a.x, g.w - a.y)) > 1e-9f;
    if (ins && spad[n] != 0.f) {
      bool hit = false;
#pragma unroll
      for (int k = 0; k < KTOP; ++k) hit |= (stopk[n * KTOP + k] == l);
      if (hit) { mps++; n_single = n; iou_single = iou; }
    }
  }

  int ns; float iou_s;
  if (mps == 0)      { ns = -1;       iou_s = 0.f; }
  else if (mps == 1) { ns = n_single; iou_s = iou_single; }
  else               { ns = max_n;    iou_s = max_iou; }  // is_max_iou replacement

  float al_s = 0.f;
  if (ns >= 0) {
    float sc = ps[((size_t)b * NL + l) * NC + sgl[ns]];
    float i2 = iou_s * iou_s;
    al_s = sc * i2 * i2 * i2;
    atomicMax(&maxm[b * NGT + ns], __float_as_uint(al_s));
    atomicMax(&maxi[b * NGT + ns], __float_as_uint(iou_s));
  }
  nstar[b * NL + l] = ns;
  astar[b * NL + l] = al_s;
}

// ------- Kernel C1: per-(b,l) scale/class + GIoU term; per-block partials ---
__global__ __launch_bounds__(256) void scale_kernel(
    const float* __restrict__ pb, const float* __restrict__ gtb,
    const int* __restrict__ gl, const int* __restrict__ nstar,
    const float* __restrict__ astar, const unsigned* __restrict__ maxm,
    const unsigned* __restrict__ maxi, float* __restrict__ scale_arr,
    int* __restrict__ jcls, double* __restrict__ part_sc)
{
  __shared__ double sred[4];
  const int b = blockIdx.y;
  const int l = blockIdx.x * 256 + threadIdx.x;
  double isum = 0.0, as = 0.0;
  if (l < NL) {
    int ns = nstar[b * NL + l];
    float scale = 0.f;
    int j = NC;
    if (ns >= 0) {
      float mm = __uint_as_float(maxm[b * NGT + ns]);
      float mi = __uint_as_float(maxi[b * NGT + ns]);
      scale = astar[b * NL + l] / (mm + 1e-9f) * mi;
      j = gl[b * NGT + ns];
      as = (double)scale;
      float4 p = ((const float4*)pb)[(size_t)b * NL + l];
      float4 g = ((const float4*)gtb)[b * NGT + ns];
      float x1 = fmaxf(p.x, g.x), y1 = fmaxf(p.y, g.y);
      float x2 = fminf(p.z, g.z), y2 = fminf(p.w, g.w);
      float ov = clamp0(x2 - x1) * clamp0(y2 - y1);
      float pa = clamp0(p.z - p.x) * clamp0(p.w - p.y);
      float ga = clamp0(g.z - g.x) * clamp0(g.w - g.y);
      float un = pa + ga - ov + 1e-10f;
      float iou = ov / un;
      float cx1 = fminf(p.x, g.x), cy1 = fminf(p.y, g.y);
      float cx2 = fmaxf(p.z, g.z), cy2 = fmaxf(p.w, g.w);
      float cc = clamp0(cx2 - cx1) * clamp0(cy2 - cy1) + 1e-10f;
      float gi = 1.f - (iou - (cc - un) / cc);
      isum = (double)(gi * scale);
    }
    scale_arr[b * NL + l] = scale;
    jcls[b * NL + l] = j;
  }
  double r0 = block_red(isum, sred);
  double r1 = block_red(as, sred);
  if (threadIdx.x == 0) {
    int blk = blockIdx.y * gridDim.x + blockIdx.x;
    part_sc[blk * 2 + 0] = r0;
    part_sc[blk * 2 + 1] = r1;
  }
}

// ---------- Kernel C2: coalesced VFL-BCE, grid-stride, block partials -------
__global__ __launch_bounds__(256) void vfl_kernel(
    const float* __restrict__ ps, const float* __restrict__ scale_arr,
    const int* __restrict__ jcls, double* __restrict__ part_vfl)
{
  __shared__ double sred[4];
  const unsigned total4 = (unsigned)NB * NL * 20;  // 5,376,000 float4 units
  double cs = 0.0;
  for (unsigned gid = blockIdx.x * 256 + threadIdx.x; gid < total4;
       gid += (unsigned)gridDim.x * 256) {
    const unsigned row = gid / 20;
    const int c0 = (int)(gid % 20) * 4;
    float4 s4 = ((const float4*)ps)[gid];
    float scale = scale_arr[row];
    int j = jcls[row];
    float sv[4] = {s4.x, s4.y, s4.z, s4.w};
    float csum = 0.f;
#pragma unroll
    for (int u = 0; u < 4; ++u) {
      float s = sv[u];
      float pcl = fminf(fmaxf(s, 1e-9f), 1.f - 1e-9f);
      float lp1 = log1pf(-pcl);
      if (c0 + u == j)
        csum += -(scale * logf(pcl) + (1.f - scale) * lp1) * scale;
      else
        csum += -lp1 * 0.75f * s * s;
    }
    cs += (double)csum;
  }
  double r = block_red(cs, sred);
  if (threadIdx.x == 0) part_vfl[blockIdx.x] = r;
}

// ---------------- Final: reduce partials, emit scalar ----------------------
__global__ __launch_bounds__(256) void fin_kernel(
    const double* __restrict__ part_vfl, const double* __restrict__ part_sc,
    float* __restrict__ out)
{
  __shared__ double sred[4];
  double cls = 0.0, isum = 0.0, as = 0.0;
  for (int i = threadIdx.x; i < VFL_BLOCKS; i += 256) cls += part_vfl[i];
  for (int i = threadIdx.x; i < SC_BLOCKS; i += 256) {
    isum += part_sc[i * 2 + 0];
    as   += part_sc[i * 2 + 1];
  }
  cls  = block_red(cls, sred);
  isum = block_red(isum, sred);
  as   = block_red(as, sred);
  if (threadIdx.x == 0) {
    double s = as > 1.0 ? as : 1.0;
    out[0] = (float)((cls + 2.5 * isum) / s);
  }
}

// ---------------------------------------------------------------------------
extern "C" void kernel_launch(void* const* d_in, const int* in_sizes, int n_in,
                              void* d_out, int out_size, void* d_ws, size_t ws_size,
                              hipStream_t stream) {
  const float* ps  = (const float*)d_in[0];   // [32,8400,80]
  const float* pbx = (const float*)d_in[1];   // [32,8400,4]
  const float* ap  = (const float*)d_in[2];   // [8400,2]
  const int*   gl  = (const int*)d_in[3];     // [32,100,1]
  const float* gtb = (const float*)d_in[4];   // [32,100,4]
  const float* pad = (const float*)d_in[5];   // [32,100,1]

  char* ws = (char*)d_ws;
  const size_t OFF_MAXM  = 0;                                 // 3200 u32
  const size_t OFF_MAXI  = OFF_MAXM + 4ul * NB * NGT;         // 3200 u32
  const size_t OFF_TOPK  = OFF_MAXI + 4ul * NB * NGT;         // 41600 i32
  const size_t OFF_NSTAR = OFF_TOPK + 4ul * NB * NGT * KTOP;  // 268800 i32
  const size_t OFF_ASTAR = OFF_NSTAR + 4ul * NB * NL;         // 268800 f32
  const size_t OFF_SCALE = OFF_ASTAR + 4ul * NB * NL;         // 268800 f32
  const size_t OFF_JCLS  = OFF_SCALE + 4ul * NB * NL;         // 268800 i32
  const size_t OFF_PVFL  = OFF_JCLS + 4ul * NB * NL;          // 2048 f64
  const size_t OFF_PSC   = OFF_PVFL + 8ul * VFL_BLOCKS;       // 2112 f64
  const size_t OFF_PST   = OFF_PSC + 8ul * SC_BLOCKS * 2;     // 86 MB f32
  const size_t PST_BYTES = 4ul * NB * NC * NL;

  unsigned* maxm  = (unsigned*)(ws + OFF_MAXM);
  unsigned* maxi  = (unsigned*)(ws + OFF_MAXI);
  int*      topk  = (int*)(ws + OFF_TOPK);
  int*      nstar = (int*)(ws + OFF_NSTAR);
  float*    astar = (float*)(ws + OFF_ASTAR);
  float*    scale_arr = (float*)(ws + OFF_SCALE);
  int*      jcls  = (int*)(ws + OFF_JCLS);
  double*   pvfl  = (double*)(ws + OFF_PVFL);
  double*   psc   = (double*)(ws + OFF_PSC);
  float*    pst   = (ws_size >= OFF_PST + PST_BYTES) ? (float*)(ws + OFF_PST) : nullptr;

  hipMemsetAsync(ws, 0, OFF_TOPK, stream);  // zero maxm + maxi

  if (pst)
    hipLaunchKernelGGL(transpose_kernel, dim3((NL + TL - 1) / TL, NB), dim3(256),
                       0, stream, ps, pst);
  hipLaunchKernelGGL(topk_kernel, dim3(NB * NGT), dim3(256), 0, stream,
                     ps, pst, pbx, ap, gl, gtb, topk);
  hipLaunchKernelGGL(assign_kernel, dim3(SC_BLOCKS_X, NB), dim3(256), 0, stream,
                     ps, pbx, ap, gl, gtb, pad, topk, nstar, astar, maxm, maxi);
  hipLaunchKernelGGL(scale_kernel, dim3(SC_BLOCKS_X, NB), dim3(256), 0, stream,
                     pbx, gtb, gl, nstar, astar, maxm, maxi, scale_arr, jcls, psc);
  hipLaunchKernelGGL(vfl_kernel, dim3(VFL_BLOCKS), dim3(256), 0, stream,
                     ps, scale_arr, jcls, pvfl);
  hipLaunchKernelGGL(fin_kernel, dim3(1), dim3(256), 0, stream, pvfl, psc,
                     (float*)d_out);
}

// Round 4
// 227.963 us; speedup vs baseline: 5.9404x; 1.2344x over previous
//
#include <hip/hip_runtime.h>

#define NB 32
#define NGT 100
#define NL 8400
#define NC 80
#define KTOP 13
#define TL 64
#define VFL_BLOCKS 2048
#define SC_BLOCKS_X 33   // ceil(8400/256)
#define SC_BLOCKS (SC_BLOCKS_X * NB)

__device__ __forceinline__ float clamp0(float x) { return fmaxf(x, 0.f); }

// Block-reduce a double (256 threads); result valid on thread 0.
__device__ __forceinline__ double block_red(double v, double* sred) {
  for (int off = 32; off > 0; off >>= 1) v += __shfl_down(v, off);
  int wid = threadIdx.x >> 6;
  if ((threadIdx.x & 63) == 0) sred[wid] = v;
  __syncthreads();
  double r = 0.0;
  if (threadIdx.x == 0) r = sred[0] + sred[1] + sred[2] + sred[3];
  __syncthreads();
  return r;
}

// ---------------- Transpose: ps [b, l, c] -> pst [b, c, l] ----------------
__global__ __launch_bounds__(256) void transpose_kernel(
    const float* __restrict__ ps, float* __restrict__ pst)
{
  __shared__ float tile[TL][NC + 1];
  const int b = blockIdx.y;
  const int l0 = blockIdx.x * TL;
  const int nl = min(TL, NL - l0);
  for (int i = threadIdx.x; i < nl * 20; i += 256) {
    int r = i / 20, cv = i % 20;
    float4 v = ((const float4*)(ps + ((size_t)b * NL + l0 + r) * NC))[cv];
    tile[r][cv * 4 + 0] = v.x; tile[r][cv * 4 + 1] = v.y;
    tile[r][cv * 4 + 2] = v.z; tile[r][cv * 4 + 3] = v.w;
  }
  __syncthreads();
  for (int i = threadIdx.x; i < NC * TL; i += 256) {
    int c = i >> 6, r = i & 63;
    if (r < nl)
      pst[((size_t)b * NC + c) * NL + l0 + r] = tile[r][c];
  }
}

// -------- Kernel A: per-(b,n) metric + single-pass top-13 selection --------
__global__ __launch_bounds__(256) void topk_kernel(
    const float* __restrict__ ps, const float* __restrict__ pst,
    const float* __restrict__ pb, const float* __restrict__ ap,
    const int* __restrict__ gl, const float* __restrict__ gtb,
    int* __restrict__ topk_out)
{
  __shared__ unsigned long long slist[256 * KTOP];
  __shared__ unsigned long long wred[4];
  const int bn = blockIdx.x;
  const int b = bn / NGT;
  const float gx1 = gtb[bn * 4 + 0], gy1 = gtb[bn * 4 + 1];
  const float gx2 = gtb[bn * 4 + 2], gy2 = gtb[bn * 4 + 3];
  const int cls = gl[bn];
  const float ga = clamp0(gx2 - gx1) * clamp0(gy2 - gy1);
  const float4* pbb = (const float4*)pb + (size_t)b * NL;
  const float* psb = ps + (size_t)b * NL * NC;
  const float* scp = pst ? pst + ((size_t)b * NC + cls) * NL : nullptr;
  const float2* apb = (const float2*)ap;

  // per-thread sorted (desc) top-13 key list; key = value_bits<<32 | ~l
  unsigned long long lst[KTOP];
#pragma unroll
  for (int j = 0; j < KTOP; ++j) lst[j] = 0ull;

  for (int l = threadIdx.x; l < NL; l += 256) {
    float4 p = pbb[l];
    float ox = fminf(p.z, gx2) - fmaxf(p.x, gx1);
    float oy = fminf(p.w, gy2) - fmaxf(p.y, gy1);
    float ov = clamp0(ox) * clamp0(oy);
    float pa = clamp0(p.z - p.x) * clamp0(p.w - p.y);
    float iou = ov / (ga + pa - ov + 1e-9f);
    float2 a = apb[l];
    float ins = (fminf(fminf(a.x - gx1, a.y - gy1),
                       fminf(gx2 - a.x, gy2 - a.y)) > 1e-9f) ? 1.f : 0.f;
    float sc = scp ? scp[l] : psb[(size_t)l * NC + cls];
    float i2 = iou * iou;
    float v = sc * i2 * i2 * i2 * ins;
    unsigned long long key =
        ((unsigned long long)__float_as_uint(v) << 32) |
        (unsigned long long)(0xFFFFFFFFu - (unsigned)l);
    if (key > lst[KTOP - 1]) {
      // branch-free sorted insert (list stays sorted desc)
#pragma unroll
      for (int j = KTOP - 1; j >= 1; --j)
        lst[j] = (key >= lst[j - 1]) ? lst[j - 1]
                                     : ((key > lst[j]) ? key : lst[j]);
      lst[0] = (key > lst[0]) ? key : lst[0];
    }
  }

  // dump sorted lists to LDS
#pragma unroll
  for (int j = 0; j < KTOP; ++j) slist[threadIdx.x * KTOP + j] = lst[j];
  __syncthreads();

  // 13 rounds: global max of 256 head keys, winner advances
  int h = 0;
  const int wid = threadIdx.x >> 6;
  for (int k = 0; k < KTOP; ++k) {
    unsigned long long head =
        (h < KTOP) ? slist[threadIdx.x * KTOP + h] : 0ull;
    unsigned long long m = head;
    for (int off = 32; off > 0; off >>= 1) {
      unsigned long long o = __shfl_down(m, off);
      if (o > m) m = o;
    }
    if ((threadIdx.x & 63) == 0) wred[wid] = m;
    __syncthreads();
    unsigned long long W = wred[0];
    if (wred[1] > W) W = wred[1];
    if (wred[2] > W) W = wred[2];
    if (wred[3] > W) W = wred[3];
    if (head == W && h < KTOP) h++;   // unique key -> unique winner
    if (threadIdx.x == 0)
      topk_out[bn * KTOP + k] = (int)(0xFFFFFFFFu - (unsigned)(W & 0xFFFFFFFFull));
    __syncthreads();
  }
}

// ------------- Kernel B: per-(b,l) assignment (n*, align*, iou*) -------------
__global__ __launch_bounds__(256) void assign_kernel(
    const float* __restrict__ ps, const float* __restrict__ pb,
    const float* __restrict__ ap, const int* __restrict__ gl,
    const float* __restrict__ gtb, const float* __restrict__ pad,
    const int* __restrict__ topk, int* __restrict__ nstar,
    float* __restrict__ astar, unsigned* __restrict__ maxm,
    unsigned* __restrict__ maxi)
{
  __shared__ float4 sgt[NGT];
  __shared__ int sgl[NGT];
  __shared__ float spad[NGT];
  __shared__ int stopk[NGT * KTOP];
  const int b = blockIdx.y;
  for (int i = threadIdx.x; i < NGT; i += 256) {
    sgt[i] = ((const float4*)gtb)[b * NGT + i];
    sgl[i] = gl[b * NGT + i];
    spad[i] = pad[b * NGT + i];
  }
  for (int i = threadIdx.x; i < NGT * KTOP; i += 256)
    stopk[i] = topk[b * NGT * KTOP + i];
  __syncthreads();

  const int l = blockIdx.x * 256 + threadIdx.x;
  if (l >= NL) return;

  float4 p = ((const float4*)pb)[(size_t)b * NL + l];
  float2 a = ((const float2*)ap)[l];
  float pa = clamp0(p.z - p.x) * clamp0(p.w - p.y);

  int mps = 0, n_single = -1, max_n = 0;
  float iou_single = 0.f, max_iou = -1.f;
  for (int n = 0; n < NGT; ++n) {
    float4 g = sgt[n];
    float ox = fminf(p.z, g.z) - fmaxf(p.x, g.x);
    float oy = fminf(p.w, g.w) - fmaxf(p.y, g.y);
    float ov = clamp0(ox) * clamp0(oy);
    float ga = clamp0(g.z - g.x) * clamp0(g.w - g.y);
    float iou = ov / (ga + pa - ov + 1e-9f);
    if (iou > max_iou) { max_iou = iou; max_n = n; }  // argmax over ALL n (incl. pad)
    bool ins = fminf(fminf(a.x - g.x, a.y - g.y),
                     fminf(g.z - a.x, g.w - a.y)) > 1e-9f;
    if (ins && spad[n] != 0.f) {
      bool hit = false;
#pragma unroll
      for (int k = 0; k < KTOP; ++k) hit |= (stopk[n * KTOP + k] == l);
      if (hit) { mps++; n_single = n; iou_single = iou; }
    }
  }

  int ns; float iou_s;
  if (mps == 0)      { ns = -1;       iou_s = 0.f; }
  else if (mps == 1) { ns = n_single; iou_s = iou_single; }
  else               { ns = max_n;    iou_s = max_iou; }  // is_max_iou replacement

  float al_s = 0.f;
  if (ns >= 0) {
    float sc = ps[((size_t)b * NL + l) * NC + sgl[ns]];
    float i2 = iou_s * iou_s;
    al_s = sc * i2 * i2 * i2;
    atomicMax(&maxm[b * NGT + ns], __float_as_uint(al_s));
    atomicMax(&maxi[b * NGT + ns], __float_as_uint(iou_s));
  }
  nstar[b * NL + l] = ns;
  astar[b * NL + l] = al_s;
}

// ------- Kernel C1: per-(b,l) scale/class + GIoU term; per-block partials ---
__global__ __launch_bounds__(256) void scale_kernel(
    const float* __restrict__ pb, const float* __restrict__ gtb,
    const int* __restrict__ gl, const int* __restrict__ nstar,
    const float* __restrict__ astar, const unsigned* __restrict__ maxm,
    const unsigned* __restrict__ maxi, float* __restrict__ scale_arr,
    int* __restrict__ jcls, double* __restrict__ part_sc)
{
  __shared__ double sred[4];
  const int b = blockIdx.y;
  const int l = blockIdx.x * 256 + threadIdx.x;
  double isum = 0.0, as = 0.0;
  if (l < NL) {
    int ns = nstar[b * NL + l];
    float scale = 0.f;
    int j = NC;
    if (ns >= 0) {
      float mm = __uint_as_float(maxm[b * NGT + ns]);
      float mi = __uint_as_float(maxi[b * NGT + ns]);
      scale = astar[b * NL + l] / (mm + 1e-9f) * mi;
      j = gl[b * NGT + ns];
      as = (double)scale;
      float4 p = ((const float4*)pb)[(size_t)b * NL + l];
      float4 g = ((const float4*)gtb)[b * NGT + ns];
      float x1 = fmaxf(p.x, g.x), y1 = fmaxf(p.y, g.y);
      float x2 = fminf(p.z, g.z), y2 = fminf(p.w, g.w);
      float ov = clamp0(x2 - x1) * clamp0(y2 - y1);
      float pa = clamp0(p.z - p.x) * clamp0(p.w - p.y);
      float ga = clamp0(g.z - g.x) * clamp0(g.w - g.y);
      float un = pa + ga - ov + 1e-10f;
      float iou = ov / un;
      float cx1 = fminf(p.x, g.x), cy1 = fminf(p.y, g.y);
      float cx2 = fmaxf(p.z, g.z), cy2 = fmaxf(p.w, g.w);
      float cc = clamp0(cx2 - cx1) * clamp0(cy2 - cy1) + 1e-10f;
      float gi = 1.f - (iou - (cc - un) / cc);
      isum = (double)(gi * scale);
    }
    scale_arr[b * NL + l] = scale;
    jcls[b * NL + l] = j;
  }
  double r0 = block_red(isum, sred);
  double r1 = block_red(as, sred);
  if (threadIdx.x == 0) {
    int blk = blockIdx.y * gridDim.x + blockIdx.x;
    part_sc[blk * 2 + 0] = r0;
    part_sc[blk * 2 + 1] = r1;
  }
}

// ---------- Kernel C2: coalesced VFL-BCE, grid-stride, block partials -------
__global__ __launch_bounds__(256) void vfl_kernel(
    const float* __restrict__ ps, const float* __restrict__ scale_arr,
    const int* __restrict__ jcls, double* __restrict__ part_vfl)
{
  __shared__ double sred[4];
  const unsigned total4 = (unsigned)NB * NL * 20;  // 5,376,000 float4 units
  double cs = 0.0;
  for (unsigned gid = blockIdx.x * 256 + threadIdx.x; gid < total4;
       gid += (unsigned)gridDim.x * 256) {
    const unsigned row = gid / 20;
    const int c0 = (int)(gid % 20) * 4;
    float4 s4 = ((const float4*)ps)[gid];
    float scale = scale_arr[row];
    int j = jcls[row];
    float sv[4] = {s4.x, s4.y, s4.z, s4.w};
    float csum = 0.f;
#pragma unroll
    for (int u = 0; u < 4; ++u) {
      float s = sv[u];
      float pcl = fminf(fmaxf(s, 1e-9f), 1.f - 1e-9f);
      float lp1 = log1pf(-pcl);
      if (c0 + u == j)
        csum += -(scale * logf(pcl) + (1.f - scale) * lp1) * scale;
      else
        csum += -lp1 * 0.75f * s * s;
    }
    cs += (double)csum;
  }
  double r = block_red(cs, sred);
  if (threadIdx.x == 0) part_vfl[blockIdx.x] = r;
}

// ---------------- Final: reduce partials, emit scalar ----------------------
__global__ __launch_bounds__(256) void fin_kernel(
    const double* __restrict__ part_vfl, const double* __restrict__ part_sc,
    float* __restrict__ out)
{
  __shared__ double sred[4];
  double cls = 0.0, isum = 0.0, as = 0.0;
  for (int i = threadIdx.x; i < VFL_BLOCKS; i += 256) cls += part_vfl[i];
  for (int i = threadIdx.x; i < SC_BLOCKS; i += 256) {
    isum += part_sc[i * 2 + 0];
    as   += part_sc[i * 2 + 1];
  }
  cls  = block_red(cls, sred);
  isum = block_red(isum, sred);
  as   = block_red(as, sred);
  if (threadIdx.x == 0) {
    double s = as > 1.0 ? as : 1.0;
    out[0] = (float)((cls + 2.5 * isum) / s);
  }
}

// ---------------------------------------------------------------------------
extern "C" void kernel_launch(void* const* d_in, const int* in_sizes, int n_in,
                              void* d_out, int out_size, void* d_ws, size_t ws_size,
                              hipStream_t stream) {
  const float* ps  = (const float*)d_in[0];   // [32,8400,80]
  const float* pbx = (const float*)d_in[1];   // [32,8400,4]
  const float* ap  = (const float*)d_in[2];   // [8400,2]
  const int*   gl  = (const int*)d_in[3];     // [32,100,1]
  const float* gtb = (const float*)d_in[4];   // [32,100,4]
  const float* pad = (const float*)d_in[5];   // [32,100,1]

  char* ws = (char*)d_ws;
  const size_t OFF_MAXM  = 0;                                 // 3200 u32
  const size_t OFF_MAXI  = OFF_MAXM + 4ul * NB * NGT;         // 3200 u32
  const size_t OFF_TOPK  = OFF_MAXI + 4ul * NB * NGT;         // 41600 i32
  const size_t OFF_NSTAR = OFF_TOPK + 4ul * NB * NGT * KTOP;  // 268800 i32
  const size_t OFF_ASTAR = OFF_NSTAR + 4ul * NB * NL;         // 268800 f32
  const size_t OFF_SCALE = OFF_ASTAR + 4ul * NB * NL;         // 268800 f32
  const size_t OFF_JCLS  = OFF_SCALE + 4ul * NB * NL;         // 268800 i32
  const size_t OFF_PVFL  = OFF_JCLS + 4ul * NB * NL;          // 2048 f64
  const size_t OFF_PSC   = OFF_PVFL + 8ul * VFL_BLOCKS;       // 2112 f64
  const size_t OFF_PST   = OFF_PSC + 8ul * SC_BLOCKS * 2;     // 86 MB f32
  const size_t PST_BYTES = 4ul * NB * NC * NL;

  unsigned* maxm  = (unsigned*)(ws + OFF_MAXM);
  unsigned* maxi  = (unsigned*)(ws + OFF_MAXI);
  int*      topk  = (int*)(ws + OFF_TOPK);
  int*      nstar = (int*)(ws + OFF_NSTAR);
  float*    astar = (float*)(ws + OFF_ASTAR);
  float*    scale_arr = (float*)(ws + OFF_SCALE);
  int*      jcls  = (int*)(ws + OFF_JCLS);
  double*   pvfl  = (double*)(ws + OFF_PVFL);
  double*   psc   = (double*)(ws + OFF_PSC);
  float*    pst   = (ws_size >= OFF_PST + PST_BYTES) ? (float*)(ws + OFF_PST) : nullptr;

  hipMemsetAsync(ws, 0, OFF_TOPK, stream);  // zero maxm + maxi

  if (pst)
    hipLaunchKernelGGL(transpose_kernel, dim3((NL + TL - 1) / TL, NB), dim3(256),
                       0, stream, ps, pst);
  hipLaunchKernelGGL(topk_kernel, dim3(NB * NGT), dim3(256), 0, stream,
                     ps, pst, pbx, ap, gl, gtb, topk);
  hipLaunchKernelGGL(assign_kernel, dim3(SC_BLOCKS_X, NB), dim3(256), 0, stream,
                     ps, pbx, ap, gl, gtb, pad, topk, nstar, astar, maxm, maxi);
  hipLaunchKernelGGL(scale_kernel, dim3(SC_BLOCKS_X, NB), dim3(256), 0, stream,
                     pbx, gtb, gl, nstar, astar, maxm, maxi, scale_arr, jcls, psc);
  hipLaunchKernelGGL(vfl_kernel, dim3(VFL_BLOCKS), dim3(256), 0, stream,
                     ps, scale_arr, jcls, pvfl);
  hipLaunchKernelGGL(fin_kernel, dim3(1), dim3(256), 0, stream, pvfl, psc,
                     (float*)d_out);
}

// Round 5
// 205.537 us; speedup vs baseline: 6.5885x; 1.1091x over previous
//
#include <hip/hip_runtime.h>

#define NB 32
#define NGT 100
#define NL 8400
#define NC 80
#define KTOP 13
#define TL 64
#define VFL_BLOCKS 2048
#define SC_BLOCKS_X 33   // ceil(8400/256)
#define SC_BLOCKS (SC_BLOCKS_X * NB)

__device__ __forceinline__ float clamp0(float x) { return fmaxf(x, 0.f); }

// Block-reduce a double (256 threads); result valid on thread 0.
__device__ __forceinline__ double block_red(double v, double* sred) {
  for (int off = 32; off > 0; off >>= 1) v += __shfl_down(v, off);
  int wid = threadIdx.x >> 6;
  if ((threadIdx.x & 63) == 0) sred[wid] = v;
  __syncthreads();
  double r = 0.0;
  if (threadIdx.x == 0) r = sred[0] + sred[1] + sred[2] + sred[3];
  __syncthreads();
  return r;
}

// ---------------- Transpose: ps [b, l, c] -> pst [b, c, l] ----------------
__global__ __launch_bounds__(256) void transpose_kernel(
    const float* __restrict__ ps, float* __restrict__ pst)
{
  __shared__ float tile[TL][NC + 1];
  const int b = blockIdx.y;
  const int l0 = blockIdx.x * TL;
  const int nl = min(TL, NL - l0);
  for (int i = threadIdx.x; i < nl * 20; i += 256) {
    int r = i / 20, cv = i % 20;
    float4 v = ((const float4*)(ps + ((size_t)b * NL + l0 + r) * NC))[cv];
    tile[r][cv * 4 + 0] = v.x; tile[r][cv * 4 + 1] = v.y;
    tile[r][cv * 4 + 2] = v.z; tile[r][cv * 4 + 3] = v.w;
  }
  __syncthreads();
  for (int i = threadIdx.x; i < NC * TL; i += 256) {
    int c = i >> 6, r = i & 63;
    if (r < nl)
      pst[((size_t)b * NC + c) * NL + l0 + r] = tile[r][c];
  }
}

// -------- Kernel A: per-(b,n) metric + single-pass top-13 (reg lists) ------
__global__ __launch_bounds__(256) void topk_kernel(
    const float* __restrict__ ps, const float* __restrict__ pst,
    const float* __restrict__ pb, const float* __restrict__ ap,
    const int* __restrict__ gl, const float* __restrict__ gtb,
    int* __restrict__ topk_out)
{
  __shared__ unsigned long long wred[4];
  const int bn = blockIdx.x;
  const int b = bn / NGT;
  const float gx1 = gtb[bn * 4 + 0], gy1 = gtb[bn * 4 + 1];
  const float gx2 = gtb[bn * 4 + 2], gy2 = gtb[bn * 4 + 3];
  const int cls = gl[bn];
  const float ga = clamp0(gx2 - gx1) * clamp0(gy2 - gy1);
  const float4* pbb = (const float4*)pb + (size_t)b * NL;
  const float* psb = ps + (size_t)b * NL * NC;
  const float* scp = pst ? pst + ((size_t)b * NC + cls) * NL : nullptr;
  const float2* apb = (const float2*)ap;

  // positive-metric keys: sorted desc u64 list; key = v_bits<<32 | ~l
  unsigned long long pl[KTOP];
  // zero-metric keys: first <=13 zeros of this lane, appended in arrival
  // order == decreasing key order (key = ~l). u32 suffices (high word 0).
  unsigned zl[KTOP];
  int zc = 0;
#pragma unroll
  for (int j = 0; j < KTOP; ++j) { pl[j] = 0ull; zl[j] = 0u; }

  for (int l = threadIdx.x; l < NL; l += 256) {
    float4 p = pbb[l];
    float ox = fminf(p.z, gx2) - fmaxf(p.x, gx1);
    float oy = fminf(p.w, gy2) - fmaxf(p.y, gy1);
    float ov = clamp0(ox) * clamp0(oy);
    float pa = clamp0(p.z - p.x) * clamp0(p.w - p.y);
    float iou = ov * __builtin_amdgcn_rcpf(ga + pa - ov + 1e-9f);
    float2 a = apb[l];
    bool ins = fminf(fminf(a.x - gx1, a.y - gy1),
                     fminf(gx2 - a.x, gy2 - a.y)) > 1e-9f;
    float sc = scp ? scp[l] : psb[(size_t)l * NC + cls];
    float i2 = iou * iou;
    float v = ins ? sc * i2 * i2 * i2 : 0.f;
    unsigned lowk = 0xFFFFFFFFu - (unsigned)l;
    if (v > 0.f) {
      unsigned long long key = ((unsigned long long)__float_as_uint(v) << 32) | lowk;
      if (key > pl[KTOP - 1]) {
#pragma unroll
        for (int j = KTOP - 1; j >= 1; --j)
          pl[j] = (key >= pl[j - 1]) ? pl[j - 1]
                                     : ((key > pl[j]) ? key : pl[j]);
        pl[0] = (key > pl[0]) ? key : pl[0];
      }
    } else if (zc < KTOP) {
      // append-only fill (arrival order is already sorted desc)
#pragma unroll
      for (int j = 0; j < KTOP; ++j) zl[j] = (zc == j) ? lowk : zl[j];
      zc++;
    }
  }

  // 13 rounds: global max over 256 lane-heads; winner shifts its list.
  // All pl keys (v>0) > all zl keys (high word 0); unfilled slots are 0.
  const int wid = threadIdx.x >> 6;
  for (int k = 0; k < KTOP; ++k) {
    unsigned long long zh = (unsigned long long)zl[0];
    bool from_p = pl[0] >= zh;
    unsigned long long head = from_p ? pl[0] : zh;
    unsigned long long m = head;
    for (int off = 32; off > 0; off >>= 1) {
      unsigned long long o = __shfl_down(m, off);
      if (o > m) m = o;
    }
    if ((threadIdx.x & 63) == 0) wred[wid] = m;
    __syncthreads();
    unsigned long long W = wred[0];
    if (wred[1] > W) W = wred[1];
    if (wred[2] > W) W = wred[2];
    if (wred[3] > W) W = wred[3];
    if (threadIdx.x == 0)
      topk_out[bn * KTOP + k] = (int)(0xFFFFFFFFu - (unsigned)(W & 0xFFFFFFFFull));
    if (head == W && W != 0ull) {  // unique nonzero key -> unique winner
      if (from_p) {
#pragma unroll
        for (int j = 0; j < KTOP - 1; ++j) pl[j] = pl[j + 1];
        pl[KTOP - 1] = 0ull;
      } else {
#pragma unroll
        for (int j = 0; j < KTOP - 1; ++j) zl[j] = zl[j + 1];
        zl[KTOP - 1] = 0u;
      }
    }
    __syncthreads();
  }
}

// ------------- Kernel B: per-(b,l) assignment (n*, align*, iou*) -------------
__global__ __launch_bounds__(256) void assign_kernel(
    const float* __restrict__ ps, const float* __restrict__ pb,
    const float* __restrict__ ap, const int* __restrict__ gl,
    const float* __restrict__ gtb, const float* __restrict__ pad,
    const int* __restrict__ topk, int* __restrict__ nstar,
    float* __restrict__ astar, unsigned* __restrict__ maxm,
    unsigned* __restrict__ maxi)
{
  __shared__ float4 sgt[NGT];
  __shared__ int sgl[NGT];
  __shared__ float spad[NGT];
  __shared__ int stopk[NGT * KTOP];
  const int b = blockIdx.y;
  for (int i = threadIdx.x; i < NGT; i += 256) {
    sgt[i] = ((const float4*)gtb)[b * NGT + i];
    sgl[i] = gl[b * NGT + i];
    spad[i] = pad[b * NGT + i];
  }
  for (int i = threadIdx.x; i < NGT * KTOP; i += 256)
    stopk[i] = topk[b * NGT * KTOP + i];
  __syncthreads();

  const int l = blockIdx.x * 256 + threadIdx.x;
  if (l >= NL) return;

  float4 p = ((const float4*)pb)[(size_t)b * NL + l];
  float2 a = ((const float2*)ap)[l];
  float pa = clamp0(p.z - p.x) * clamp0(p.w - p.y);

  int mps = 0, n_single = -1, max_n = 0;
  float iou_single = 0.f, max_iou = -1.f;
  for (int n = 0; n < NGT; ++n) {
    float4 g = sgt[n];
    float ox = fminf(p.z, g.z) - fmaxf(p.x, g.x);
    float oy = fminf(p.w, g.w) - fmaxf(p.y, g.y);
    float ov = clamp0(ox) * clamp0(oy);
    float ga = clamp0(g.z - g.x) * clamp0(g.w - g.y);
    float iou = ov / (ga + pa - ov + 1e-9f);
    if (iou > max_iou) { max_iou = iou; max_n = n; }  // argmax over ALL n (incl. pad)
    bool ins = fminf(fminf(a.x - g.x, a.y - g.y),
                     fminf(g.z - a.x, g.w - a.y)) > 1e-9f;
    if (ins && spad[n] != 0.f) {
      bool hit = false;
#pragma unroll
      for (int k = 0; k < KTOP; ++k) hit |= (stopk[n * KTOP + k] == l);
      if (hit) { mps++; n_single = n; iou_single = iou; }
    }
  }

  int ns; float iou_s;
  if (mps == 0)      { ns = -1;       iou_s = 0.f; }
  else if (mps == 1) { ns = n_single; iou_s = iou_single; }
  else               { ns = max_n;    iou_s = max_iou; }  // is_max_iou replacement

  float al_s = 0.f;
  if (ns >= 0) {
    float sc = ps[((size_t)b * NL + l) * NC + sgl[ns]];
    float i2 = iou_s * iou_s;
    al_s = sc * i2 * i2 * i2;
    atomicMax(&maxm[b * NGT + ns], __float_as_uint(al_s));
    atomicMax(&maxi[b * NGT + ns], __float_as_uint(iou_s));
  }
  nstar[b * NL + l] = ns;
  astar[b * NL + l] = al_s;
}

// ------- Kernel C1: per-(b,l) scale/class + GIoU term; per-block partials ---
__global__ __launch_bounds__(256) void scale_kernel(
    const float* __restrict__ pb, const float* __restrict__ gtb,
    const int* __restrict__ gl, const int* __restrict__ nstar,
    const float* __restrict__ astar, const unsigned* __restrict__ maxm,
    const unsigned* __restrict__ maxi, float* __restrict__ scale_arr,
    int* __restrict__ jcls, double* __restrict__ part_sc)
{
  __shared__ double sred[4];
  const int b = blockIdx.y;
  const int l = blockIdx.x * 256 + threadIdx.x;
  double isum = 0.0, as = 0.0;
  if (l < NL) {
    int ns = nstar[b * NL + l];
    float scale = 0.f;
    int j = NC;
    if (ns >= 0) {
      float mm = __uint_as_float(maxm[b * NGT + ns]);
      float mi = __uint_as_float(maxi[b * NGT + ns]);
      scale = astar[b * NL + l] / (mm + 1e-9f) * mi;
      j = gl[b * NGT + ns];
      as = (double)scale;
      float4 p = ((const float4*)pb)[(size_t)b * NL + l];
      float4 g = ((const float4*)gtb)[b * NGT + ns];
      float x1 = fmaxf(p.x, g.x), y1 = fmaxf(p.y, g.y);
      float x2 = fminf(p.z, g.z), y2 = fminf(p.w, g.w);
      float ov = clamp0(x2 - x1) * clamp0(y2 - y1);
      float pa = clamp0(p.z - p.x) * clamp0(p.w - p.y);
      float ga = clamp0(g.z - g.x) * clamp0(g.w - g.y);
      float un = pa + ga - ov + 1e-10f;
      float iou = ov / un;
      float cx1 = fminf(p.x, g.x), cy1 = fminf(p.y, g.y);
      float cx2 = fmaxf(p.z, g.z), cy2 = fmaxf(p.w, g.w);
      float cc = clamp0(cx2 - cx1) * clamp0(cy2 - cy1) + 1e-10f;
      float gi = 1.f - (iou - (cc - un) / cc);
      isum = (double)(gi * scale);
    }
    scale_arr[b * NL + l] = scale;
    jcls[b * NL + l] = j;
  }
  double r0 = block_red(isum, sred);
  double r1 = block_red(as, sred);
  if (threadIdx.x == 0) {
    int blk = blockIdx.y * gridDim.x + blockIdx.x;
    part_sc[blk * 2 + 0] = r0;
    part_sc[blk * 2 + 1] = r1;
  }
}

// ---------- Kernel C2: coalesced VFL-BCE, grid-stride, block partials -------
__global__ __launch_bounds__(256) void vfl_kernel(
    const float* __restrict__ ps, const float* __restrict__ scale_arr,
    const int* __restrict__ jcls, double* __restrict__ part_vfl)
{
  __shared__ double sred[4];
  const unsigned total4 = (unsigned)NB * NL * 20;  // 5,376,000 float4 units
  double cs = 0.0;
  for (unsigned gid = blockIdx.x * 256 + threadIdx.x; gid < total4;
       gid += (unsigned)gridDim.x * 256) {
    const unsigned row = gid / 20;
    const int c0 = (int)(gid % 20) * 4;
    float4 s4 = ((const float4*)ps)[gid];
    float scale = scale_arr[row];
    int j = jcls[row];
    float sv[4] = {s4.x, s4.y, s4.z, s4.w};
    float csum = 0.f;
#pragma unroll
    for (int u = 0; u < 4; ++u) {
      float s = sv[u];
      float pcl = fminf(fmaxf(s, 1e-9f), 1.f - 1e-9f);
      float lp1 = log1pf(-pcl);
      if (c0 + u == j)
        csum += -(scale * logf(pcl) + (1.f - scale) * lp1) * scale;
      else
        csum += -lp1 * 0.75f * s * s;
    }
    cs += (double)csum;
  }
  double r = block_red(cs, sred);
  if (threadIdx.x == 0) part_vfl[blockIdx.x] = r;
}

// ---------------- Final: reduce partials, emit scalar ----------------------
__global__ __launch_bounds__(256) void fin_kernel(
    const double* __restrict__ part_vfl, const double* __restrict__ part_sc,
    float* __restrict__ out)
{
  __shared__ double sred[4];
  double cls = 0.0, isum = 0.0, as = 0.0;
  for (int i = threadIdx.x; i < VFL_BLOCKS; i += 256) cls += part_vfl[i];
  for (int i = threadIdx.x; i < SC_BLOCKS; i += 256) {
    isum += part_sc[i * 2 + 0];
    as   += part_sc[i * 2 + 1];
  }
  cls  = block_red(cls, sred);
  isum = block_red(isum, sred);
  as   = block_red(as, sred);
  if (threadIdx.x == 0) {
    double s = as > 1.0 ? as : 1.0;
    out[0] = (float)((cls + 2.5 * isum) / s);
  }
}

// ---------------------------------------------------------------------------
extern "C" void kernel_launch(void* const* d_in, const int* in_sizes, int n_in,
                              void* d_out, int out_size, void* d_ws, size_t ws_size,
                              hipStream_t stream) {
  const float* ps  = (const float*)d_in[0];   // [32,8400,80]
  const float* pbx = (const float*)d_in[1];   // [32,8400,4]
  const float* ap  = (const float*)d_in[2];   // [8400,2]
  const int*   gl  = (const int*)d_in[3];     // [32,100,1]
  const float* gtb = (const float*)d_in[4];   // [32,100,4]
  const float* pad = (const float*)d_in[5];   // [32,100,1]

  char* ws = (char*)d_ws;
  const size_t OFF_MAXM  = 0;                                 // 3200 u32
  const size_t OFF_MAXI  = OFF_MAXM + 4ul * NB * NGT;         // 3200 u32
  const size_t OFF_TOPK  = OFF_MAXI + 4ul * NB * NGT;         // 41600 i32
  const size_t OFF_NSTAR = OFF_TOPK + 4ul * NB * NGT * KTOP;  // 268800 i32
  const size_t OFF_ASTAR = OFF_NSTAR + 4ul * NB * NL;         // 268800 f32
  const size_t OFF_SCALE = OFF_ASTAR + 4ul * NB * NL;         // 268800 f32
  const size_t OFF_JCLS  = OFF_SCALE + 4ul * NB * NL;         // 268800 i32
  const size_t OFF_PVFL  = OFF_JCLS + 4ul * NB * NL;          // 2048 f64
  const size_t OFF_PSC   = OFF_PVFL + 8ul * VFL_BLOCKS;       // 2112 f64
  const size_t OFF_PST   = OFF_PSC + 8ul * SC_BLOCKS * 2;     // 86 MB f32
  const size_t PST_BYTES = 4ul * NB * NC * NL;

  unsigned* maxm  = (unsigned*)(ws + OFF_MAXM);
  unsigned* maxi  = (unsigned*)(ws + OFF_MAXI);
  int*      topk  = (int*)(ws + OFF_TOPK);
  int*      nstar = (int*)(ws + OFF_NSTAR);
  float*    astar = (float*)(ws + OFF_ASTAR);
  float*    scale_arr = (float*)(ws + OFF_SCALE);
  int*      jcls  = (int*)(ws + OFF_JCLS);
  double*   pvfl  = (double*)(ws + OFF_PVFL);
  double*   psc   = (double*)(ws + OFF_PSC);
  float*    pst   = (ws_size >= OFF_PST + PST_BYTES) ? (float*)(ws + OFF_PST) : nullptr;

  hipMemsetAsync(ws, 0, OFF_TOPK, stream);  // zero maxm + maxi

  if (pst)
    hipLaunchKernelGGL(transpose_kernel, dim3((NL + TL - 1) / TL, NB), dim3(256),
                       0, stream, ps, pst);
  hipLaunchKernelGGL(topk_kernel, dim3(NB * NGT), dim3(256), 0, stream,
                     ps, pst, pbx, ap, gl, gtb, topk);
  hipLaunchKernelGGL(assign_kernel, dim3(SC_BLOCKS_X, NB), dim3(256), 0, stream,
                     ps, pbx, ap, gl, gtb, pad, topk, nstar, astar, maxm, maxi);
  hipLaunchKernelGGL(scale_kernel, dim3(SC_BLOCKS_X, NB), dim3(256), 0, stream,
                     pbx, gtb, gl, nstar, astar, maxm, maxi, scale_arr, jcls, psc);
  hipLaunchKernelGGL(vfl_kernel, dim3(VFL_BLOCKS), dim3(256), 0, stream,
                     ps, scale_arr, jcls, pvfl);
  hipLaunchKernelGGL(fin_kernel, dim3(1), dim3(256), 0, stream, pvfl, psc,
                     (float*)d_out);
}